// Round 7
// baseline (1512.939 us; speedup 1.0000x reference)
//
#include <hip/hip_runtime.h>
#include <cstdint>

typedef __bf16 bf16x8 __attribute__((ext_vector_type(8)));
typedef float f32x4 __attribute__((ext_vector_type(4)));
typedef unsigned short ushort8 __attribute__((ext_vector_type(8)));

#define DEV __device__ __forceinline__
#define MFMA16(a, b, c) __builtin_amdgcn_mfma_f32_16x16x32_bf16((a), (b), (c), 0, 0, 0)
// MFMA with B operand forced to AGPR class (weights resident in AGPRs, no per-use copies)
#define MFMA_AG(acc, hf, wf) \
  asm("v_mfma_f32_16x16x32_bf16 %0, %1, %2, %0" : "+v"(acc) : "v"(hf), "a"(wf))

DEV unsigned short f2b(float x) {
  union { float f; unsigned int u; } c; c.f = x;
  unsigned int u = c.u + 0x7fffu + ((c.u >> 16) & 1u);
  return (unsigned short)(u >> 16);
}
DEV float b2f(unsigned short x) {
  union { unsigned int u; float f; } c; c.u = ((unsigned int)x) << 16;
  return c.f;
}
DEV void gld_lds16(const void* g, void* l) {
  __builtin_amdgcn_global_load_lds(
      (const __attribute__((address_space(1))) unsigned int*)(uintptr_t)g,
      (__attribute__((address_space(3))) unsigned int*)(uintptr_t)l, 16, 0, 0);
}

// ---------------- weight conversion ----------------
// f32 [K][N] -> bf16 [N][K] (transposed)
__global__ __launch_bounds__(256) void convT_k(const float* __restrict__ in,
                                               unsigned short* __restrict__ out,
                                               int K, int N) {
  __shared__ float tile[64][65];
  int k0 = blockIdx.x * 64, n0 = blockIdx.y * 64;
  int wv = threadIdx.x >> 6, ln = threadIdx.x & 63;
  #pragma unroll
  for (int i = 0; i < 16; ++i) {
    int r = wv * 16 + i;
    tile[r][ln] = in[(size_t)(k0 + r) * N + (n0 + ln)];
  }
  __syncthreads();
  #pragma unroll
  for (int i = 0; i < 16; ++i) {
    int r = wv * 16 + i;
    out[(size_t)(n0 + r) * K + (k0 + ln)] = f2b(tile[ln][r]);
  }
}

__global__ void convB_k(const float* __restrict__ in, unsigned short* __restrict__ out, int n) {
  int stride = gridDim.x * blockDim.x;
  for (int i = blockIdx.x * blockDim.x + threadIdx.x; i < n; i += stride)
    out[i] = f2b(in[i]);
}

// combined GRU input bias: cb[i][c] = bih[i][c] + (c<512 ? bhh[i][c] : 0)
__global__ __launch_bounds__(256) void biasC_k(const float* __restrict__ bih,
                                               const float* __restrict__ bhh,
                                               float* __restrict__ cb) {
  int i = blockIdx.x * 256 + threadIdx.x;
  if (i < 4 * 768) {
    int c = i % 768;
    cb[i] = bih[i] + (c < 512 ? bhh[i] : 0.f);
  }
}

// ---------------- embedding gather ----------------
__global__ __launch_bounds__(256) void embed_k(const int* __restrict__ x, const float* __restrict__ emb,
                                               float* __restrict__ cf, unsigned short* __restrict__ cb) {
  int row = blockIdx.x * 4 + (threadIdx.x >> 6);
  int lane = threadIdx.x & 63;
  int tok = x[row];
  const float4* src = (const float4*)(emb + (size_t)tok * 512 + lane * 8);
  float4 a = src[0], b = src[1];
  float4* dst = (float4*)(cf + (size_t)row * 512 + lane * 8);
  dst[0] = a; dst[1] = b;
  ushort8 pk;
  pk[0] = f2b(a.x); pk[1] = f2b(a.y); pk[2] = f2b(a.z); pk[3] = f2b(a.w);
  pk[4] = f2b(b.x); pk[5] = f2b(b.y); pk[6] = f2b(b.z); pk[7] = f2b(b.w);
  *(ushort8*)(cb + (size_t)row * 512 + lane * 8) = pk;
}

// ---------------- GEMM: A[M,K]bf16 @ B (BT[N,K] bf16) + bias (+res) -> f32/bf16 ----------------
DEV void stage_tile(const unsigned short* g, int ld, unsigned short* lds, int lane, int wave) {
  #pragma unroll
  for (int i = 0; i < 2; ++i) {
    int r0 = (i * 4 + wave) * 16;
    const unsigned short* src = g + (size_t)(r0 + (lane >> 2)) * ld + (lane & 3) * 8;
    gld_lds16(src, lds + r0 * 32);
  }
}

template <int RELU, int RES, int OF32, int OB16>
__global__ __launch_bounds__(256) void gemm_k(
    const unsigned short* __restrict__ A, const unsigned short* __restrict__ BT,
    const float* __restrict__ bias, const float* __restrict__ res,
    float* __restrict__ Cf, unsigned short* __restrict__ Cb,
    int M, int N, int K) {
  __shared__ unsigned short sA[2][128 * 32];
  __shared__ unsigned short sB[2][128 * 32];
  int tid = threadIdx.x, lane = tid & 63, wave = tid >> 6;
  int m0 = blockIdx.x * 128, n0 = blockIdx.y * 128;
  int lm = lane & 15, lk = (lane >> 4) * 8;
  int wr = wave >> 1, wc = wave & 1;
  f32x4 acc[4][4];
  #pragma unroll
  for (int i = 0; i < 4; ++i)
    #pragma unroll
    for (int j = 0; j < 4; ++j) acc[i][j] = (f32x4){0.f, 0.f, 0.f, 0.f};
  const unsigned short* Ab = A + (size_t)m0 * K;
  const unsigned short* Bb = BT + (size_t)n0 * K;
  int nk = K >> 5;
  stage_tile(Ab, K, sA[0], lane, wave);
  stage_tile(Bb, K, sB[0], lane, wave);
  __syncthreads();
  int buf = 0;
  for (int t = 0; t < nk; ++t) {
    if (t + 1 < nk) {
      stage_tile(Ab + (t + 1) * 32, K, sA[buf ^ 1], lane, wave);
      stage_tile(Bb + (t + 1) * 32, K, sB[buf ^ 1], lane, wave);
    }
    bf16x8 aF[4], bF[4];
    #pragma unroll
    for (int i = 0; i < 4; ++i) aF[i] = *(const bf16x8*)&sA[buf][(wr * 64 + i * 16 + lm) * 32 + lk];
    #pragma unroll
    for (int j = 0; j < 4; ++j) bF[j] = *(const bf16x8*)&sB[buf][(wc * 64 + j * 16 + lm) * 32 + lk];
    #pragma unroll
    for (int i = 0; i < 4; ++i)
      #pragma unroll
      for (int j = 0; j < 4; ++j) acc[i][j] = MFMA16(aF[i], bF[j], acc[i][j]);
    __syncthreads();
    buf ^= 1;
  }
  #pragma unroll
  for (int i = 0; i < 4; ++i) {
    int gr0 = m0 + wr * 64 + i * 16 + (lane >> 4) * 4;
    #pragma unroll
    for (int j = 0; j < 4; ++j) {
      int gc = n0 + wc * 64 + j * 16 + lm;
      float bv = bias[gc];
      #pragma unroll
      for (int q = 0; q < 4; ++q) {
        size_t idx = (size_t)(gr0 + q) * N + gc;
        float v = acc[i][j][q] + bv;
        if (RES) v += res[idx];
        if (RELU) v = fmaxf(v, 0.f);
        if (OF32) Cf[idx] = v;
        if (OB16) Cb[idx] = f2b(v);
      }
    }
  }
}

// ---------------- attention: per group g of [100,64], contiguous-view split ----------------
__global__ __launch_bounds__(256) void attn_k(const unsigned short* __restrict__ Q,
                                              const unsigned short* __restrict__ Kv,
                                              const unsigned short* __restrict__ V,
                                              unsigned short* __restrict__ ctx) {
  __shared__ unsigned short Ks[112 * 64];
  __shared__ unsigned short VT[64 * 128];
  __shared__ unsigned short Ps[112 * 128];
  int g = blockIdx.x;
  size_t base = (size_t)g * 6400;
  int tid = threadIdx.x, lane = tid & 63, wave = tid >> 6;
  int lm = lane & 15, lg = lane >> 4, lk = lg * 8;
  for (int idx = tid; idx < 112 * 8; idx += 256) {
    int row = idx >> 3, c8 = (idx & 7) * 8;
    int rr = row < 100 ? row : 99;
    *(ushort8*)&Ks[row * 64 + c8] = *(const ushort8*)&Kv[base + (size_t)rr * 64 + c8];
  }
  for (int idx = tid; idx < 64 * 28; idx += 256) { int c = idx / 28, j = idx % 28; VT[c * 128 + 100 + j] = 0; }
  for (int idx = tid; idx < 112 * 16; idx += 256) { int r = idx / 16, c = idx % 16; Ps[r * 128 + 112 + c] = 0; }
  for (int idx = tid; idx < 6400; idx += 256) {
    int c = idx / 100, j = idx % 100;
    VT[c * 128 + j] = V[base + (size_t)j * 64 + c];
  }
  __syncthreads();
  for (int rt = wave; rt < 7; rt += 4) {
    int arow = rt * 16 + lm;
    int qrow = arow < 100 ? arow : 99;
    bf16x8 aF0 = *(const bf16x8*)&Q[base + (size_t)qrow * 64 + lk];
    bf16x8 aF1 = *(const bf16x8*)&Q[base + (size_t)qrow * 64 + 32 + lk];
    f32x4 sc[7];
    #pragma unroll
    for (int ct = 0; ct < 7; ++ct) {
      bf16x8 b0 = *(const bf16x8*)&Ks[(ct * 16 + lm) * 64 + lk];
      bf16x8 b1 = *(const bf16x8*)&Ks[(ct * 16 + lm) * 64 + 32 + lk];
      f32x4 a = {0.f, 0.f, 0.f, 0.f};
      a = MFMA16(aF0, b0, a);
      a = MFMA16(aF1, b1, a);
      sc[ct] = a;
    }
    #pragma unroll
    for (int q = 0; q < 4; ++q) {
      float mx = -1e30f;
      #pragma unroll
      for (int ct = 0; ct < 7; ++ct) {
        int col = ct * 16 + lm;
        float v = sc[ct][q] * 0.125f;
        if (col < 100) mx = fmaxf(mx, v);
      }
      for (int off = 1; off < 16; off <<= 1) mx = fmaxf(mx, __shfl_xor(mx, off));
      float sum = 0.f; float pv[7];
      #pragma unroll
      for (int ct = 0; ct < 7; ++ct) {
        int col = ct * 16 + lm;
        float e = (col < 100) ? __expf(sc[ct][q] * 0.125f - mx) : 0.f;
        pv[ct] = e; sum += e;
      }
      for (int off = 1; off < 16; off <<= 1) sum += __shfl_xor(sum, off);
      float inv = 1.f / sum;
      int prow = rt * 16 + lg * 4 + q;
      #pragma unroll
      for (int ct = 0; ct < 7; ++ct) Ps[prow * 128 + ct * 16 + lm] = f2b(pv[ct] * inv);
    }
  }
  __syncthreads();
  for (int rt = wave; rt < 7; rt += 4) {
    bf16x8 aP[4];
    #pragma unroll
    for (int kc = 0; kc < 4; ++kc) aP[kc] = *(const bf16x8*)&Ps[(rt * 16 + lm) * 128 + kc * 32 + lk];
    #pragma unroll
    for (int ctp = 0; ctp < 4; ++ctp) {
      f32x4 o = {0.f, 0.f, 0.f, 0.f};
      #pragma unroll
      for (int kc = 0; kc < 4; ++kc) {
        bf16x8 bV = *(const bf16x8*)&VT[(ctp * 16 + lm) * 128 + kc * 32 + lk];
        o = MFMA16(aP[kc], bV, o);
      }
      #pragma unroll
      for (int q = 0; q < 4; ++q) {
        int ri = rt * 16 + lg * 4 + q;
        if (ri < 100) ctx[base + (size_t)ri * 64 + ctp * 16 + lm] = f2b(o[q]);
      }
    }
  }
}

// ---------------- LayerNorm over D=512 ----------------
__global__ __launch_bounds__(256) void ln_k(const float* __restrict__ in, const float* __restrict__ gamma,
                                            const float* __restrict__ beta, float* __restrict__ outF,
                                            unsigned short* __restrict__ outB) {
  int row = blockIdx.x * 4 + (threadIdx.x >> 6);
  int lane = threadIdx.x & 63;
  const float* p = in + (size_t)row * 512 + lane * 8;
  float4 v0 = *(const float4*)p;
  float4 v1 = *(const float4*)(p + 4);
  float x[8] = {v0.x, v0.y, v0.z, v0.w, v1.x, v1.y, v1.z, v1.w};
  float s = 0.f;
  #pragma unroll
  for (int e = 0; e < 8; ++e) s += x[e];
  #pragma unroll
  for (int off = 1; off < 64; off <<= 1) s += __shfl_xor(s, off);
  float mean = s * (1.f / 512.f);
  float vs = 0.f;
  #pragma unroll
  for (int e = 0; e < 8; ++e) { float d = x[e] - mean; vs += d * d; }
  #pragma unroll
  for (int off = 1; off < 64; off <<= 1) vs += __shfl_xor(vs, off);
  float rstd = rsqrtf(vs * (1.f / 512.f) + 1e-5f);
  int c0 = lane * 8;
  ushort8 pk;
  #pragma unroll
  for (int e = 0; e < 8; ++e) {
    float y = (x[e] - mean) * rstd * gamma[c0 + e] + beta[c0 + e];
    x[e] = y; pk[e] = f2b(y);
  }
  float4* po = (float4*)(outF + (size_t)row * 512 + c0);
  po[0] = make_float4(x[0], x[1], x[2], x[3]);
  po[1] = make_float4(x[4], x[5], x[6], x[7]);
  *(ushort8*)(outB + (size_t)row * 512 + c0) = pk;
}

// ---------------- [B,S,D] bf16 -> [S,B,D] bf16 ----------------
__global__ __launch_bounds__(128) void seqT_k(const unsigned short* __restrict__ in,
                                              unsigned short* __restrict__ out) {
  int o = blockIdx.x;
  int s = o >> 7, b = o & 127;
  const uint2* src = (const uint2*)(in + (size_t)(b * 100 + s) * 512);
  uint2* dst = (uint2*)(out + (size_t)o * 512);
  dst[threadIdx.x] = src[threadIdx.x];
}

// ---------------- GRU scan v7 ----------------
// 16 WGs (dir x 8 bsl of 16 rows), 4 waves/WG (256 thr), waves_per_eu(1,1) -> 512-reg
// budget/wave. Round-6 diagnosis: at 124v+128a=252/256 the compiler had 4 spare regs
// -> JIT ds_reads serialized each step (~6.7K cy vs ~2K cy of work). Now: r,z weights
// = 256 AGPRs (4 ct x 8 kt x 2 gates); ~200 VGPRs hold hoisted hF[8], streamed n
// fragments, xv(48), acc(48), hprev(16), with ~56 spare for compiler pipelining.
// n gate in LDS (128KB, per-wave 32KB linear, conflict-free b128). xp loaded at step
// top (latency covered by the ~1000cy MFMA/read phase). One lgkmcnt(0)+barrier/step.
__global__ __launch_bounds__(256) __attribute__((amdgpu_waves_per_eu(1, 1))) void gru_k(
    const unsigned short* __restrict__ WhhB,  // [2][768][256] bf16
    const float* __restrict__ bhh,            // [2][768] (only n-gate slice used)
    const float* __restrict__ xp,             // [2][100][128][768] f32, bias = bih + bhh(r,z)
    unsigned short* __restrict__ hout)        // [100][128][512] bf16
{
  __shared__ unsigned short hb[2][16 * 256];  // swizzled h state (16KB)
  __shared__ char ldsn[131072];               // n-gate weights (128KB)
  const int dir = blockIdx.x >> 3, bsl = blockIdx.x & 7;
  const int tid = threadIdx.x, lane = tid & 63, w = tid >> 6;  // 4 waves
  const int lm = lane & 15, lg = lane >> 4, lk = lg * 8;

  for (int i = tid; i < 16 * 256; i += 256) hb[0][i] = 0;

  // stage n-gate weights into LDS: wave w owns region [w*32KB, +32KB)
  {
    const unsigned short* wn = WhhB + (size_t)(dir * 768 + 512) * 256;
    #pragma unroll
    for (int ct = 0; ct < 4; ++ct)
      #pragma unroll
      for (int kt = 0; kt < 8; ++kt) {
        const unsigned short* src = wn + (size_t)(w * 64 + ct * 16 + lm) * 256 + kt * 32 + lk;
        gld_lds16(src, ldsn + (size_t)w * 32768 + (ct * 8 + kt) * 1024);
      }
  }

  // r,z weights -> 256 AGPRs (keep-live "+a" pins class; all uses are "a"-constrained)
  bf16x8 wr[4][8], wz[4][8];
  #pragma unroll
  for (int ct = 0; ct < 4; ++ct) {
    const unsigned short* wpr = WhhB + (size_t)(dir * 768 + w * 64 + ct * 16 + lm) * 256;
    const unsigned short* wpz = WhhB + (size_t)(dir * 768 + 256 + w * 64 + ct * 16 + lm) * 256;
    #pragma unroll
    for (int kt = 0; kt < 8; ++kt) {
      wr[ct][kt] = *(const bf16x8*)&wpr[kt * 32 + lk];
      wz[ct][kt] = *(const bf16x8*)&wpz[kt * 32 + lk];
    }
  }
  #pragma unroll
  for (int ct = 0; ct < 4; ++ct)
    #pragma unroll
    for (int kt = 0; kt < 8; ++kt) {
      asm("" : "+a"(wr[ct][kt]));
      asm("" : "+a"(wz[ct][kt]));
    }

  float bh2[4];
  #pragma unroll
  for (int ct = 0; ct < 4; ++ct) bh2[ct] = bhh[dir * 768 + 512 + w * 64 + ct * 16 + lm];
  float hprev[4][4];
  #pragma unroll
  for (int ct = 0; ct < 4; ++ct)
    #pragma unroll
    for (int q = 0; q < 4; ++q) hprev[ct][q] = 0.f;

  const int s0 = dir ? 99 : 0, sstep = dir ? -1 : 1;
  unsigned short* hob = hout + ((size_t)(s0 * 128 + bsl * 16 + lg * 4)) * 512 + dir * 256 + w * 64 + lm;
  const ptrdiff_t hstep = (ptrdiff_t)sstep * 65536;
  const float* xpb = xp + ((size_t)dir * 100 + s0) * 98304 + (size_t)(bsl * 16 + lg * 4) * 768 + w * 64 + lm;
  const ptrdiff_t xstep = (ptrdiff_t)sstep * 98304;

  __syncthreads();  // drains vmcnt(0)+lgkmcnt(0): n-weights staged, hb[0] zeros visible

  const int swz = (lm & 7) << 4;
  const char* nb = ldsn + (size_t)w * 32768 + lane * 16;
  for (int t = 0; t < 100; ++t) {
    const int cur = t & 1;
    // xp(t) loads: issued first, consumed in the gate phase (compiler-managed waits)
    float xv[3][4][4];
    #pragma unroll
    for (int g = 0; g < 3; ++g)
      #pragma unroll
      for (int ct = 0; ct < 4; ++ct)
        #pragma unroll
        for (int q = 0; q < 4; ++q)
          xv[g][ct][q] = xpb[q * 768 + g * 256 + ct * 16];
    // hoist ALL h fragments (8 ds_read_b128 issued back-to-back, latency overlapped)
    const char* hbase = (const char*)&hb[cur][0] + lm * 512;
    bf16x8 hF[8];
    #pragma unroll
    for (int kt = 0; kt < 8; ++kt)
      hF[kt] = *(const bf16x8*)(hbase + ((kt * 64 + lg * 16) ^ swz));
    // MFMA phase: r,z pure-AGPR (no LDS dep after hF), n streams from LDS
    f32x4 aR[4], aZ[4], aN[4];
    #pragma unroll
    for (int ct = 0; ct < 4; ++ct) {
      aR[ct] = (f32x4){0.f, 0.f, 0.f, 0.f};
      aZ[ct] = (f32x4){0.f, 0.f, 0.f, 0.f};
      aN[ct] = (f32x4){0.f, 0.f, 0.f, 0.f};
    }
    #pragma unroll
    for (int kt = 0; kt < 8; ++kt) {
      bf16x8 n0 = *(const bf16x8*)(nb + (0 * 8 + kt) * 1024);
      bf16x8 n1 = *(const bf16x8*)(nb + (1 * 8 + kt) * 1024);
      bf16x8 n2 = *(const bf16x8*)(nb + (2 * 8 + kt) * 1024);
      bf16x8 n3 = *(const bf16x8*)(nb + (3 * 8 + kt) * 1024);
      #pragma unroll
      for (int ct = 0; ct < 4; ++ct) {
        MFMA_AG(aR[ct], hF[kt], wr[ct][kt]);
        MFMA_AG(aZ[ct], hF[kt], wz[ct][kt]);
      }
      aN[0] = MFMA16(hF[kt], n0, aN[0]);
      aN[1] = MFMA16(hF[kt], n1, aN[1]);
      aN[2] = MFMA16(hF[kt], n2, aN[2]);
      aN[3] = MFMA16(hF[kt], n3, aN[3]);
    }
    // gate phase: 16 elements/lane (4 ct x 4 q)
    #pragma unroll
    for (int ct = 0; ct < 4; ++ct) {
      #pragma unroll
      for (int q = 0; q < 4; ++q) {
        const int row = lg * 4 + q;
        const int hoff = (w * 128 + ct * 32 + lm * 2) ^ ((row & 7) << 4);
        float r = 1.f / (1.f + __expf(-(xv[0][ct][q] + aR[ct][q])));
        float z = 1.f / (1.f + __expf(-(xv[1][ct][q] + aZ[ct][q])));
        float nbv = xv[2][ct][q] + r * (aN[ct][q] + bh2[ct]);
        float n = 1.f - 2.f / (__expf(2.f * nbv) + 1.f);
        float hn = (1.f - z) * n + z * hprev[ct][q];
        hprev[ct][q] = hn;
        unsigned short hbits = f2b(hn);
        *(unsigned short*)((char*)&hb[cur ^ 1][0] + row * 512 + hoff) = hbits;
        hob[q * 512 + ct * 16] = hbits;
      }
    }
    asm volatile("s_waitcnt lgkmcnt(0)" ::: "memory");  // h writes visible before barrier
    __builtin_amdgcn_s_barrier();
    hob += hstep;
    xpb += xstep;
  }
}

// ---------------- relu+concat+maxpool over seq ----------------
__global__ __launch_bounds__(256) void pool_k(const float* __restrict__ ef, const unsigned short* __restrict__ h2,
                                              float* __restrict__ pooled) {
  int b = blockIdx.x, tid = threadIdx.x;
  for (int c = tid; c < 1024; c += 256) {
    float m = 0.f;
    if (c < 512) {
      for (int s = 0; s < 100; ++s) m = fmaxf(m, ef[((size_t)b * 100 + s) * 512 + c]);
    } else {
      int cc = c - 512;
      for (int s = 0; s < 100; ++s) m = fmaxf(m, b2f(h2[((size_t)s * 128 + b) * 512 + cc]));
    }
    pooled[b * 1024 + c] = m;
  }
}

// ---------------- final FC [128,1024] @ [1024,10] + b ----------------
__global__ __launch_bounds__(64) void fc_k(const float* __restrict__ pooled, const float* __restrict__ W,
                                           const float* __restrict__ bias, float* __restrict__ out) {
  int b = blockIdx.x, lane = threadIdx.x;
  float a[10];
  #pragma unroll
  for (int n = 0; n < 10; ++n) a[n] = 0.f;
  for (int k = lane; k < 1024; k += 64) {
    float pv = pooled[b * 1024 + k];
    const float* wr = W + k * 10;
    #pragma unroll
    for (int n = 0; n < 10; ++n) a[n] += pv * wr[n];
  }
  #pragma unroll
  for (int n = 0; n < 10; ++n)
    for (int off = 32; off > 0; off >>= 1) a[n] += __shfl_xor(a[n], off);
  if (lane == 0) {
    #pragma unroll
    for (int n = 0; n < 10; ++n) out[b * 10 + n] = a[n] + bias[n];
  }
}

// ---------------- host ----------------
extern "C" void kernel_launch(void* const* d_in, const int* in_sizes, int n_in,
                              void* d_out, int out_size, void* d_ws, size_t ws_size,
                              hipStream_t stream) {
  (void)in_sizes; (void)n_in; (void)out_size;
  const int*   x   = (const int*)d_in[0];
  const float* emb = (const float*)d_in[2];
  const float* Wq  = (const float*)d_in[3];  const float* bq  = (const float*)d_in[4];
  const float* Wk  = (const float*)d_in[5];  const float* bk  = (const float*)d_in[6];
  const float* Wv  = (const float*)d_in[7];  const float* bv  = (const float*)d_in[8];
  const float* Wo  = (const float*)d_in[9];  const float* bo  = (const float*)d_in[10];
  const float* g1  = (const float*)d_in[11]; const float* be1 = (const float*)d_in[12];
  const float* W1  = (const float*)d_in[13]; const float* b1  = (const float*)d_in[14];
  const float* W2  = (const float*)d_in[15]; const float* b2  = (const float*)d_in[16];
  const float* g2  = (const float*)d_in[17]; const float* be2 = (const float*)d_in[18];
  const float* Wih = (const float*)d_in[19]; const float* Whh = (const float*)d_in[20];
  const float* bih = (const float*)d_in[21]; const float* bhh = (const float*)d_in[22];
  const float* fcW = (const float*)d_in[23]; const float* fcb = (const float*)d_in[24];

  if (ws_size < 193986560ULL) return;
  char* ws = (char*)d_ws;

  const size_t O_CURF = 0, O_CURBF = 26214400, O_WQT = 39321600, O_WKT = 40894464,
               O_WVT = 42467328, O_WOT = 44040192, O_W1T = 45613056, O_W2T = 51904512,
               O_WIH = 58195968, O_WHH = 61341696, O_A = 62914560;
  float* cur_f = (float*)(ws + O_CURF);
  unsigned short* cur_bf = (unsigned short*)(ws + O_CURBF);
  unsigned short* WqT = (unsigned short*)(ws + O_WQT);
  unsigned short* WkT = (unsigned short*)(ws + O_WKT);
  unsigned short* WvT = (unsigned short*)(ws + O_WVT);
  unsigned short* WoT = (unsigned short*)(ws + O_WOT);
  unsigned short* W1T = (unsigned short*)(ws + O_W1T);
  unsigned short* W2T = (unsigned short*)(ws + O_W2T);
  unsigned short* WihB = (unsigned short*)(ws + O_WIH);
  unsigned short* WhhB = (unsigned short*)(ws + O_WHH);
  // cbias reuses the WqT region (dead after the encoder loop; biasC_k runs after it)
  float* cbias = (float*)(ws + O_WQT);
  unsigned short* Qb  = (unsigned short*)(ws + O_A);
  unsigned short* Kb  = (unsigned short*)(ws + O_A + 13107200);
  unsigned short* Vb  = (unsigned short*)(ws + O_A + 26214400);
  unsigned short* ctx = (unsigned short*)(ws + O_A + 39321600);
  unsigned short* ff1 = (unsigned short*)(ws + O_A + 52428800);
  float* tmp_f = (float*)(ws + O_A + 104857600);
  unsigned short* xseq  = (unsigned short*)(ws + O_A);
  float* xp             = (float*)(ws + O_A + 13107200);
  unsigned short* hout1 = (unsigned short*)(ws + O_A + 91750400);
  unsigned short* hout2 = (unsigned short*)(ws + O_A + 104857600);
  float* pooled         = (float*)(ws + O_A + 117964800);

  for (int l = 0; l < 3; ++l) {
    convT_k<<<dim3(8, 8), 256, 0, stream>>>(Wq + (size_t)l * 262144, WqT + (size_t)l * 262144, 512, 512);
    convT_k<<<dim3(8, 8), 256, 0, stream>>>(Wk + (size_t)l * 262144, WkT + (size_t)l * 262144, 512, 512);
    convT_k<<<dim3(8, 8), 256, 0, stream>>>(Wv + (size_t)l * 262144, WvT + (size_t)l * 262144, 512, 512);
    convT_k<<<dim3(8, 8), 256, 0, stream>>>(Wo + (size_t)l * 262144, WoT + (size_t)l * 262144, 512, 512);
    convT_k<<<dim3(8, 32), 256, 0, stream>>>(W1 + (size_t)l * 1048576, W1T + (size_t)l * 1048576, 512, 2048);
    convT_k<<<dim3(32, 8), 256, 0, stream>>>(W2 + (size_t)l * 1048576, W2T + (size_t)l * 1048576, 2048, 512);
  }
  convB_k<<<1024, 256, 0, stream>>>(Wih, WihB, 2 * 2 * 768 * 512);
  convB_k<<<512, 256, 0, stream>>>(Whh, WhhB, 2 * 2 * 768 * 256);

  embed_k<<<3200, 256, 0, stream>>>(x, emb, cur_f, cur_bf);

  for (int l = 0; l < 3; ++l) {
    gemm_k<0, 0, 0, 1><<<dim3(100, 4), 256, 0, stream>>>(cur_bf, WqT + (size_t)l * 262144, bq + l * 512, nullptr, nullptr, Qb, 12800, 512, 512);
    gemm_k<0, 0, 0, 1><<<dim3(100, 4), 256, 0, stream>>>(cur_bf, WkT + (size_t)l * 262144, bk + l * 512, nullptr, nullptr, Kb, 12800, 512, 512);
    gemm_k<0, 0, 0, 1><<<dim3(100, 4), 256, 0, stream>>>(cur_bf, WvT + (size_t)l * 262144, bv + l * 512, nullptr, nullptr, Vb, 12800, 512, 512);
    attn_k<<<1024, 256, 0, stream>>>(Qb, Kb, Vb, ctx);
    gemm_k<0, 1, 1, 0><<<dim3(100, 4), 256, 0, stream>>>(ctx, WoT + (size_t)l * 262144, bo + l * 512, cur_f, tmp_f, nullptr, 12800, 512, 512);
    ln_k<<<3200, 256, 0, stream>>>(tmp_f, g1 + l * 512, be1 + l * 512, cur_f, cur_bf);
    gemm_k<1, 0, 0, 1><<<dim3(100, 16), 256, 0, stream>>>(cur_bf, W1T + (size_t)l * 1048576, b1 + l * 2048, nullptr, nullptr, ff1, 12800, 2048, 512);
    gemm_k<0, 1, 1, 0><<<dim3(100, 4), 256, 0, stream>>>(ff1, W2T + (size_t)l * 1048576, b2 + l * 512, cur_f, tmp_f, nullptr, 12800, 512, 2048);
    ln_k<<<3200, 256, 0, stream>>>(tmp_f, g2 + l * 512, be2 + l * 512, cur_f, cur_bf);
  }

  // GRU stage (encoder scratch now dead; cbias written into WqT region)
  biasC_k<<<12, 256, 0, stream>>>(bih, bhh, cbias);
  seqT_k<<<12800, 128, 0, stream>>>(cur_bf, xseq);
  for (int l = 0; l < 2; ++l) {
    const unsigned short* Ain = (l == 0) ? xseq : hout1;
    for (int d = 0; d < 2; ++d)
      gemm_k<0, 0, 1, 0><<<dim3(100, 6), 256, 0, stream>>>(
          Ain, WihB + ((size_t)l * 2 + d) * 768 * 512, cbias + (l * 2 + d) * 768, nullptr,
          xp + (size_t)d * 9830400, nullptr, 12800, 768, 512);
    gru_k<<<16, 256, 0, stream>>>(WhhB + (size_t)l * 2 * 768 * 256, bhh + l * 2 * 768, xp,
                                  (l == 0) ? hout1 : hout2);
  }

  pool_k<<<128, 256, 0, stream>>>(cur_f, hout2, pooled);
  fc_k<<<128, 64, 0, stream>>>(pooled, fcW, fcb, (float*)d_out);
}

// Round 8
// 1381.416 us; speedup vs baseline: 1.0952x; 1.0952x over previous
//
#include <hip/hip_runtime.h>
#include <cstdint>

typedef __bf16 bf16x8 __attribute__((ext_vector_type(8)));
typedef float f32x4 __attribute__((ext_vector_type(4)));
typedef unsigned short ushort8 __attribute__((ext_vector_type(8)));

#define DEV __device__ __forceinline__
#define MFMA16(a, b, c) __builtin_amdgcn_mfma_f32_16x16x32_bf16((a), (b), (c), 0, 0, 0)
// MFMA with B operand forced to AGPR class (weights resident in AGPRs, no per-use copies)
#define MFMA_AG(acc, hf, wf) \
  asm("v_mfma_f32_16x16x32_bf16 %0, %1, %2, %0" : "+v"(acc) : "v"(hf), "a"(wf))

DEV unsigned short f2b(float x) {
  union { float f; unsigned int u; } c; c.f = x;
  unsigned int u = c.u + 0x7fffu + ((c.u >> 16) & 1u);
  return (unsigned short)(u >> 16);
}
DEV float b2f(unsigned short x) {
  union { unsigned int u; float f; } c; c.u = ((unsigned int)x) << 16;
  return c.f;
}
DEV void gld_lds16(const void* g, void* l) {
  __builtin_amdgcn_global_load_lds(
      (const __attribute__((address_space(1))) unsigned int*)(uintptr_t)g,
      (__attribute__((address_space(3))) unsigned int*)(uintptr_t)l, 16, 0, 0);
}

// ---------------- weight conversion ----------------
// f32 [K][N] -> bf16 [N][K] (transposed)
__global__ __launch_bounds__(256) void convT_k(const float* __restrict__ in,
                                               unsigned short* __restrict__ out,
                                               int K, int N) {
  __shared__ float tile[64][65];
  int k0 = blockIdx.x * 64, n0 = blockIdx.y * 64;
  int wv = threadIdx.x >> 6, ln = threadIdx.x & 63;
  #pragma unroll
  for (int i = 0; i < 16; ++i) {
    int r = wv * 16 + i;
    tile[r][ln] = in[(size_t)(k0 + r) * N + (n0 + ln)];
  }
  __syncthreads();
  #pragma unroll
  for (int i = 0; i < 16; ++i) {
    int r = wv * 16 + i;
    out[(size_t)(n0 + r) * K + (k0 + ln)] = f2b(tile[ln][r]);
  }
}

__global__ void convB_k(const float* __restrict__ in, unsigned short* __restrict__ out, int n) {
  int stride = gridDim.x * blockDim.x;
  for (int i = blockIdx.x * blockDim.x + threadIdx.x; i < n; i += stride)
    out[i] = f2b(in[i]);
}

// combined GRU input bias: cb[i][c] = bih[i][c] + (c<512 ? bhh[i][c] : 0)
__global__ __launch_bounds__(256) void biasC_k(const float* __restrict__ bih,
                                               const float* __restrict__ bhh,
                                               float* __restrict__ cb) {
  int i = blockIdx.x * 256 + threadIdx.x;
  if (i < 4 * 768) {
    int c = i % 768;
    cb[i] = bih[i] + (c < 512 ? bhh[i] : 0.f);
  }
}

// ---------------- embedding gather ----------------
__global__ __launch_bounds__(256) void embed_k(const int* __restrict__ x, const float* __restrict__ emb,
                                               float* __restrict__ cf, unsigned short* __restrict__ cb) {
  int row = blockIdx.x * 4 + (threadIdx.x >> 6);
  int lane = threadIdx.x & 63;
  int tok = x[row];
  const float4* src = (const float4*)(emb + (size_t)tok * 512 + lane * 8);
  float4 a = src[0], b = src[1];
  float4* dst = (float4*)(cf + (size_t)row * 512 + lane * 8);
  dst[0] = a; dst[1] = b;
  ushort8 pk;
  pk[0] = f2b(a.x); pk[1] = f2b(a.y); pk[2] = f2b(a.z); pk[3] = f2b(a.w);
  pk[4] = f2b(b.x); pk[5] = f2b(b.y); pk[6] = f2b(b.z); pk[7] = f2b(b.w);
  *(ushort8*)(cb + (size_t)row * 512 + lane * 8) = pk;
}

// ---------------- GEMM: A[M,K]bf16 @ B (BT[N,K] bf16) + bias (+res) -> f32/bf16 ----------------
DEV void stage_tile(const unsigned short* g, int ld, unsigned short* lds, int lane, int wave) {
  #pragma unroll
  for (int i = 0; i < 2; ++i) {
    int r0 = (i * 4 + wave) * 16;
    const unsigned short* src = g + (size_t)(r0 + (lane >> 2)) * ld + (lane & 3) * 8;
    gld_lds16(src, lds + r0 * 32);
  }
}

template <int RELU, int RES, int OF32, int OB16>
__global__ __launch_bounds__(256) void gemm_k(
    const unsigned short* __restrict__ A, const unsigned short* __restrict__ BT,
    const float* __restrict__ bias, const float* __restrict__ res,
    float* __restrict__ Cf, unsigned short* __restrict__ Cb,
    int M, int N, int K) {
  __shared__ unsigned short sA[2][128 * 32];
  __shared__ unsigned short sB[2][128 * 32];
  int tid = threadIdx.x, lane = tid & 63, wave = tid >> 6;
  int m0 = blockIdx.x * 128, n0 = blockIdx.y * 128;
  int lm = lane & 15, lk = (lane >> 4) * 8;
  int wr = wave >> 1, wc = wave & 1;
  f32x4 acc[4][4];
  #pragma unroll
  for (int i = 0; i < 4; ++i)
    #pragma unroll
    for (int j = 0; j < 4; ++j) acc[i][j] = (f32x4){0.f, 0.f, 0.f, 0.f};
  const unsigned short* Ab = A + (size_t)m0 * K;
  const unsigned short* Bb = BT + (size_t)n0 * K;
  int nk = K >> 5;
  stage_tile(Ab, K, sA[0], lane, wave);
  stage_tile(Bb, K, sB[0], lane, wave);
  __syncthreads();
  int buf = 0;
  for (int t = 0; t < nk; ++t) {
    if (t + 1 < nk) {
      stage_tile(Ab + (t + 1) * 32, K, sA[buf ^ 1], lane, wave);
      stage_tile(Bb + (t + 1) * 32, K, sB[buf ^ 1], lane, wave);
    }
    bf16x8 aF[4], bF[4];
    #pragma unroll
    for (int i = 0; i < 4; ++i) aF[i] = *(const bf16x8*)&sA[buf][(wr * 64 + i * 16 + lm) * 32 + lk];
    #pragma unroll
    for (int j = 0; j < 4; ++j) bF[j] = *(const bf16x8*)&sB[buf][(wc * 64 + j * 16 + lm) * 32 + lk];
    #pragma unroll
    for (int i = 0; i < 4; ++i)
      #pragma unroll
      for (int j = 0; j < 4; ++j) acc[i][j] = MFMA16(aF[i], bF[j], acc[i][j]);
    __syncthreads();
    buf ^= 1;
  }
  #pragma unroll
  for (int i = 0; i < 4; ++i) {
    int gr0 = m0 + wr * 64 + i * 16 + (lane >> 4) * 4;
    #pragma unroll
    for (int j = 0; j < 4; ++j) {
      int gc = n0 + wc * 64 + j * 16 + lm;
      float bv = bias[gc];
      #pragma unroll
      for (int q = 0; q < 4; ++q) {
        size_t idx = (size_t)(gr0 + q) * N + gc;
        float v = acc[i][j][q] + bv;
        if (RES) v += res[idx];
        if (RELU) v = fmaxf(v, 0.f);
        if (OF32) Cf[idx] = v;
        if (OB16) Cb[idx] = f2b(v);
      }
    }
  }
}

// ---------------- attention: per group g of [100,64], contiguous-view split ----------------
__global__ __launch_bounds__(256) void attn_k(const unsigned short* __restrict__ Q,
                                              const unsigned short* __restrict__ Kv,
                                              const unsigned short* __restrict__ V,
                                              unsigned short* __restrict__ ctx) {
  __shared__ unsigned short Ks[112 * 64];
  __shared__ unsigned short VT[64 * 128];
  __shared__ unsigned short Ps[112 * 128];
  int g = blockIdx.x;
  size_t base = (size_t)g * 6400;
  int tid = threadIdx.x, lane = tid & 63, wave = tid >> 6;
  int lm = lane & 15, lg = lane >> 4, lk = lg * 8;
  for (int idx = tid; idx < 112 * 8; idx += 256) {
    int row = idx >> 3, c8 = (idx & 7) * 8;
    int rr = row < 100 ? row : 99;
    *(ushort8*)&Ks[row * 64 + c8] = *(const ushort8*)&Kv[base + (size_t)rr * 64 + c8];
  }
  for (int idx = tid; idx < 64 * 28; idx += 256) { int c = idx / 28, j = idx % 28; VT[c * 128 + 100 + j] = 0; }
  for (int idx = tid; idx < 112 * 16; idx += 256) { int r = idx / 16, c = idx % 16; Ps[r * 128 + 112 + c] = 0; }
  for (int idx = tid; idx < 6400; idx += 256) {
    int c = idx / 100, j = idx % 100;
    VT[c * 128 + j] = V[base + (size_t)j * 64 + c];
  }
  __syncthreads();
  for (int rt = wave; rt < 7; rt += 4) {
    int arow = rt * 16 + lm;
    int qrow = arow < 100 ? arow : 99;
    bf16x8 aF0 = *(const bf16x8*)&Q[base + (size_t)qrow * 64 + lk];
    bf16x8 aF1 = *(const bf16x8*)&Q[base + (size_t)qrow * 64 + 32 + lk];
    f32x4 sc[7];
    #pragma unroll
    for (int ct = 0; ct < 7; ++ct) {
      bf16x8 b0 = *(const bf16x8*)&Ks[(ct * 16 + lm) * 64 + lk];
      bf16x8 b1 = *(const bf16x8*)&Ks[(ct * 16 + lm) * 64 + 32 + lk];
      f32x4 a = {0.f, 0.f, 0.f, 0.f};
      a = MFMA16(aF0, b0, a);
      a = MFMA16(aF1, b1, a);
      sc[ct] = a;
    }
    #pragma unroll
    for (int q = 0; q < 4; ++q) {
      float mx = -1e30f;
      #pragma unroll
      for (int ct = 0; ct < 7; ++ct) {
        int col = ct * 16 + lm;
        float v = sc[ct][q] * 0.125f;
        if (col < 100) mx = fmaxf(mx, v);
      }
      for (int off = 1; off < 16; off <<= 1) mx = fmaxf(mx, __shfl_xor(mx, off));
      float sum = 0.f; float pv[7];
      #pragma unroll
      for (int ct = 0; ct < 7; ++ct) {
        int col = ct * 16 + lm;
        float e = (col < 100) ? __expf(sc[ct][q] * 0.125f - mx) : 0.f;
        pv[ct] = e; sum += e;
      }
      for (int off = 1; off < 16; off <<= 1) sum += __shfl_xor(sum, off);
      float inv = 1.f / sum;
      int prow = rt * 16 + lg * 4 + q;
      #pragma unroll
      for (int ct = 0; ct < 7; ++ct) Ps[prow * 128 + ct * 16 + lm] = f2b(pv[ct] * inv);
    }
  }
  __syncthreads();
  for (int rt = wave; rt < 7; rt += 4) {
    bf16x8 aP[4];
    #pragma unroll
    for (int kc = 0; kc < 4; ++kc) aP[kc] = *(const bf16x8*)&Ps[(rt * 16 + lm) * 128 + kc * 32 + lk];
    #pragma unroll
    for (int ctp = 0; ctp < 4; ++ctp) {
      f32x4 o = {0.f, 0.f, 0.f, 0.f};
      #pragma unroll
      for (int kc = 0; kc < 4; ++kc) {
        bf16x8 bV = *(const bf16x8*)&VT[(ctp * 16 + lm) * 128 + kc * 32 + lk];
        o = MFMA16(aP[kc], bV, o);
      }
      #pragma unroll
      for (int q = 0; q < 4; ++q) {
        int ri = rt * 16 + lg * 4 + q;
        if (ri < 100) ctx[base + (size_t)ri * 64 + ctp * 16 + lm] = f2b(o[q]);
      }
    }
  }
}

// ---------------- LayerNorm over D=512 ----------------
__global__ __launch_bounds__(256) void ln_k(const float* __restrict__ in, const float* __restrict__ gamma,
                                            const float* __restrict__ beta, float* __restrict__ outF,
                                            unsigned short* __restrict__ outB) {
  int row = blockIdx.x * 4 + (threadIdx.x >> 6);
  int lane = threadIdx.x & 63;
  const float* p = in + (size_t)row * 512 + lane * 8;
  float4 v0 = *(const float4*)p;
  float4 v1 = *(const float4*)(p + 4);
  float x[8] = {v0.x, v0.y, v0.z, v0.w, v1.x, v1.y, v1.z, v1.w};
  float s = 0.f;
  #pragma unroll
  for (int e = 0; e < 8; ++e) s += x[e];
  #pragma unroll
  for (int off = 1; off < 64; off <<= 1) s += __shfl_xor(s, off);
  float mean = s * (1.f / 512.f);
  float vs = 0.f;
  #pragma unroll
  for (int e = 0; e < 8; ++e) { float d = x[e] - mean; vs += d * d; }
  #pragma unroll
  for (int off = 1; off < 64; off <<= 1) vs += __shfl_xor(vs, off);
  float rstd = rsqrtf(vs * (1.f / 512.f) + 1e-5f);
  int c0 = lane * 8;
  ushort8 pk;
  #pragma unroll
  for (int e = 0; e < 8; ++e) {
    float y = (x[e] - mean) * rstd * gamma[c0 + e] + beta[c0 + e];
    x[e] = y; pk[e] = f2b(y);
  }
  float4* po = (float4*)(outF + (size_t)row * 512 + c0);
  po[0] = make_float4(x[0], x[1], x[2], x[3]);
  po[1] = make_float4(x[4], x[5], x[6], x[7]);
  *(ushort8*)(outB + (size_t)row * 512 + c0) = pk;
}

// ---------------- [B,S,D] bf16 -> [S,B,D] bf16 ----------------
__global__ __launch_bounds__(128) void seqT_k(const unsigned short* __restrict__ in,
                                              unsigned short* __restrict__ out) {
  int o = blockIdx.x;
  int s = o >> 7, b = o & 127;
  const uint2* src = (const uint2*)(in + (size_t)(b * 100 + s) * 512);
  uint2* dst = (uint2*)(out + (size_t)o * 512);
  dst[threadIdx.x] = src[threadIdx.x];
}

// ---------------- GRU scan v8 ----------------
// Round-6 config (best TLP: 8 waves, wpe(2,2), r/z in 128 AGPRs via "a"-operand MFMA,
// n-gate in 128KB LDS) + per-step instruction diet. Round-7 A/B proved TLP(2) >
// register headroom; counters showed VALU-issue-bound (~64% per-CU VALUBusy) with
// ~600cy/SIMD/step of structural overhead. Column->lane remap col = w*32 + lm*2 + ct
// (consecutive PAIR per lane; only the weight fragment loads permute -- B-fragment
// lane<->column assignment is free). Buys: xv as 12 dwordx2 (was 24 scalar), hout as
// 8x4B packed stores (was 16x2B), h->LDS as 8 cvt_pk_bf16_f32 + 8 ds_write_b32 (was
// 16 f2b + 16 b16 writes), h_prev in 8 regs (was 16 ds_read_u16 + b2f), no xp LDS
// staging (direct global loads, consumed ~1500cy after issue). ~244/256 regs.
__global__ __launch_bounds__(512) __attribute__((amdgpu_waves_per_eu(2, 2))) void gru_k(
    const unsigned short* __restrict__ WhhB,  // [2][768][256] bf16
    const float* __restrict__ bhh,            // [2][768] (only n-gate slice used)
    const float* __restrict__ xp,             // [2][100][128][768] f32, bias = bih + bhh(r,z)
    unsigned short* __restrict__ hout)        // [100][128][512] bf16
{
  __shared__ unsigned short hb[2][16 * 256];  // swizzled h state (16KB)
  __shared__ char ldsn[131072];               // n-gate weights (128KB)
  const int dir = blockIdx.x >> 3, bsl = blockIdx.x & 7;
  const int tid = threadIdx.x, lane = tid & 63, w = tid >> 6;  // 8 waves
  const int lm = lane & 15, lg = lane >> 4, lk = lg * 8;
  const int col = w * 32 + lm * 2;  // ct=0 column (pair mapping: ct in {0,1})

  for (int i = tid; i < 16 * 256; i += 512) hb[0][i] = 0;

  // stage n-gate weights into LDS: wave w owns [w*16KB, +16KB); block (ct,kt) = 1KB
  {
    const unsigned short* wn = WhhB + (size_t)(dir * 768 + 512) * 256;
    #pragma unroll
    for (int ct = 0; ct < 2; ++ct)
      #pragma unroll
      for (int kt = 0; kt < 8; ++kt) {
        const unsigned short* src = wn + (size_t)(col + ct) * 256 + kt * 32 + lk;
        gld_lds16(src, ldsn + (size_t)w * 16384 + (ct * 8 + kt) * 1024);
      }
  }

  // r,z weights -> 128 AGPRs (keep-live "+a" pins class; all uses "a"-constrained)
  bf16x8 wr[2][8], wz[2][8];
  #pragma unroll
  for (int ct = 0; ct < 2; ++ct) {
    const unsigned short* wpr = WhhB + (size_t)(dir * 768 + col + ct) * 256;
    const unsigned short* wpz = WhhB + (size_t)(dir * 768 + 256 + col + ct) * 256;
    #pragma unroll
    for (int kt = 0; kt < 8; ++kt) {
      wr[ct][kt] = *(const bf16x8*)&wpr[kt * 32 + lk];
      wz[ct][kt] = *(const bf16x8*)&wpz[kt * 32 + lk];
    }
  }
  #pragma unroll
  for (int ct = 0; ct < 2; ++ct)
    #pragma unroll
    for (int kt = 0; kt < 8; ++kt) {
      asm("" : "+a"(wr[ct][kt]));
      asm("" : "+a"(wz[ct][kt]));
    }

  float bh2[2];
  bh2[0] = bhh[dir * 768 + 512 + col];
  bh2[1] = bhh[dir * 768 + 512 + col + 1];
  float hprev[2][4] = {{0.f, 0.f, 0.f, 0.f}, {0.f, 0.f, 0.f, 0.f}};

  const int s0 = dir ? 99 : 0, sstep = dir ? -1 : 1;
  unsigned short* hob = hout + ((size_t)(s0 * 128 + bsl * 16 + lg * 4)) * 512 + dir * 256 + col;
  const ptrdiff_t hstep = (ptrdiff_t)sstep * 65536;
  const float* xpb = xp + ((size_t)dir * 100 + s0) * 98304 + (size_t)(bsl * 16 + lg * 4) * 768 + col;
  const ptrdiff_t xstep = (ptrdiff_t)sstep * 98304;

  __syncthreads();  // drains vmcnt(0)+lgkmcnt(0): n-weights staged, hb[0] zeros visible

  const int swz = (lm & 7) << 4;
  const char* nb = ldsn + (size_t)w * 16384 + lane * 16;
  for (int t = 0; t < 100; ++t) {
    const int cur = t & 1;
    // xp(t): 12 dwordx2 (pairs of consecutive true cols), consumed in gate phase
    float2 xv[3][4];
    #pragma unroll
    for (int g = 0; g < 3; ++g)
      #pragma unroll
      for (int q = 0; q < 4; ++q)
        xv[g][q] = *(const float2*)(xpb + q * 768 + g * 256);
    // hoist all h fragments (8 ds_read_b128)
    const char* hbase = (const char*)&hb[cur][0] + lm * 512;
    bf16x8 hF[8];
    #pragma unroll
    for (int kt = 0; kt < 8; ++kt)
      hF[kt] = *(const bf16x8*)(hbase + ((kt * 64 + lg * 16) ^ swz));
    // MFMA phase: r,z pure-AGPR; n streams from LDS
    f32x4 aR[2], aZ[2], aN[2];
    #pragma unroll
    for (int ct = 0; ct < 2; ++ct) {
      aR[ct] = (f32x4){0.f, 0.f, 0.f, 0.f};
      aZ[ct] = (f32x4){0.f, 0.f, 0.f, 0.f};
      aN[ct] = (f32x4){0.f, 0.f, 0.f, 0.f};
    }
    #pragma unroll
    for (int kt = 0; kt < 8; ++kt) {
      bf16x8 n0 = *(const bf16x8*)(nb + kt * 1024);
      bf16x8 n1 = *(const bf16x8*)(nb + 8192 + kt * 1024);
      MFMA_AG(aR[0], hF[kt], wr[0][kt]);
      MFMA_AG(aZ[0], hF[kt], wz[0][kt]);
      MFMA_AG(aR[1], hF[kt], wr[1][kt]);
      MFMA_AG(aZ[1], hF[kt], wz[1][kt]);
      aN[0] = MFMA16(hF[kt], n0, aN[0]);
      aN[1] = MFMA16(hF[kt], n1, aN[1]);
    }
    // gate phase: 8 elements/lane (2 ct x 4 q), packed write per q
    #pragma unroll
    for (int q = 0; q < 4; ++q) {
      const int row = lg * 4 + q;
      float hn01[2];
      #pragma unroll
      for (int ct = 0; ct < 2; ++ct) {
        float xr = (ct ? xv[0][q].y : xv[0][q].x);
        float xz = (ct ? xv[1][q].y : xv[1][q].x);
        float xn = (ct ? xv[2][q].y : xv[2][q].x);
        float r = 1.f / (1.f + __expf(-(xr + aR[ct][q])));
        float z = 1.f / (1.f + __expf(-(xz + aZ[ct][q])));
        float nbv = xn + r * (aN[ct][q] + bh2[ct]);
        float n = 1.f - 2.f / (__expf(2.f * nbv) + 1.f);
        float hn = (1.f - z) * n + z * hprev[ct][q];
        hprev[ct][q] = hn;
        hn01[ct] = hn;
      }
      unsigned int pk;
      asm("v_cvt_pk_bf16_f32 %0, %1, %2" : "=v"(pk) : "v"(hn01[0]), "v"(hn01[1]));
      *(unsigned int*)((char*)&hb[cur ^ 1][0] + row * 512 + ((w * 64 + lm * 4) ^ ((row & 7) << 4))) = pk;
      *(unsigned int*)&hob[q * 512] = pk;
    }
    asm volatile("s_waitcnt lgkmcnt(0)" ::: "memory");  // h writes visible before barrier
    __builtin_amdgcn_s_barrier();
    hob += hstep;
    xpb += xstep;
  }
}

// ---------------- relu+concat+maxpool over seq ----------------
__global__ __launch_bounds__(256) void pool_k(const float* __restrict__ ef, const unsigned short* __restrict__ h2,
                                              float* __restrict__ pooled) {
  int b = blockIdx.x, tid = threadIdx.x;
  for (int c = tid; c < 1024; c += 256) {
    float m = 0.f;
    if (c < 512) {
      for (int s = 0; s < 100; ++s) m = fmaxf(m, ef[((size_t)b * 100 + s) * 512 + c]);
    } else {
      int cc = c - 512;
      for (int s = 0; s < 100; ++s) m = fmaxf(m, b2f(h2[((size_t)s * 128 + b) * 512 + cc]));
    }
    pooled[b * 1024 + c] = m;
  }
}

// ---------------- final FC [128,1024] @ [1024,10] + b ----------------
__global__ __launch_bounds__(64) void fc_k(const float* __restrict__ pooled, const float* __restrict__ W,
                                           const float* __restrict__ bias, float* __restrict__ out) {
  int b = blockIdx.x, lane = threadIdx.x;
  float a[10];
  #pragma unroll
  for (int n = 0; n < 10; ++n) a[n] = 0.f;
  for (int k = lane; k < 1024; k += 64) {
    float pv = pooled[b * 1024 + k];
    const float* wr = W + k * 10;
    #pragma unroll
    for (int n = 0; n < 10; ++n) a[n] += pv * wr[n];
  }
  #pragma unroll
  for (int n = 0; n < 10; ++n)
    for (int off = 32; off > 0; off >>= 1) a[n] += __shfl_xor(a[n], off);
  if (lane == 0) {
    #pragma unroll
    for (int n = 0; n < 10; ++n) out[b * 10 + n] = a[n] + bias[n];
  }
}

// ---------------- host ----------------
extern "C" void kernel_launch(void* const* d_in, const int* in_sizes, int n_in,
                              void* d_out, int out_size, void* d_ws, size_t ws_size,
                              hipStream_t stream) {
  (void)in_sizes; (void)n_in; (void)out_size;
  const int*   x   = (const int*)d_in[0];
  const float* emb = (const float*)d_in[2];
  const float* Wq  = (const float*)d_in[3];  const float* bq  = (const float*)d_in[4];
  const float* Wk  = (const float*)d_in[5];  const float* bk  = (const float*)d_in[6];
  const float* Wv  = (const float*)d_in[7];  const float* bv  = (const float*)d_in[8];
  const float* Wo  = (const float*)d_in[9];  const float* bo  = (const float*)d_in[10];
  const float* g1  = (const float*)d_in[11]; const float* be1 = (const float*)d_in[12];
  const float* W1  = (const float*)d_in[13]; const float* b1  = (const float*)d_in[14];
  const float* W2  = (const float*)d_in[15]; const float* b2  = (const float*)d_in[16];
  const float* g2  = (const float*)d_in[17]; const float* be2 = (const float*)d_in[18];
  const float* Wih = (const float*)d_in[19]; const float* Whh = (const float*)d_in[20];
  const float* bih = (const float*)d_in[21]; const float* bhh = (const float*)d_in[22];
  const float* fcW = (const float*)d_in[23]; const float* fcb = (const float*)d_in[24];

  if (ws_size < 193986560ULL) return;
  char* ws = (char*)d_ws;

  const size_t O_CURF = 0, O_CURBF = 26214400, O_WQT = 39321600, O_WKT = 40894464,
               O_WVT = 42467328, O_WOT = 44040192, O_W1T = 45613056, O_W2T = 51904512,
               O_WIH = 58195968, O_WHH = 61341696, O_A = 62914560;
  float* cur_f = (float*)(ws + O_CURF);
  unsigned short* cur_bf = (unsigned short*)(ws + O_CURBF);
  unsigned short* WqT = (unsigned short*)(ws + O_WQT);
  unsigned short* WkT = (unsigned short*)(ws + O_WKT);
  unsigned short* WvT = (unsigned short*)(ws + O_WVT);
  unsigned short* WoT = (unsigned short*)(ws + O_WOT);
  unsigned short* W1T = (unsigned short*)(ws + O_W1T);
  unsigned short* W2T = (unsigned short*)(ws + O_W2T);
  unsigned short* WihB = (unsigned short*)(ws + O_WIH);
  unsigned short* WhhB = (unsigned short*)(ws + O_WHH);
  // cbias reuses the WqT region (dead after the encoder loop; biasC_k runs after it)
  float* cbias = (float*)(ws + O_WQT);
  unsigned short* Qb  = (unsigned short*)(ws + O_A);
  unsigned short* Kb  = (unsigned short*)(ws + O_A + 13107200);
  unsigned short* Vb  = (unsigned short*)(ws + O_A + 26214400);
  unsigned short* ctx = (unsigned short*)(ws + O_A + 39321600);
  unsigned short* ff1 = (unsigned short*)(ws + O_A + 52428800);
  float* tmp_f = (float*)(ws + O_A + 104857600);
  unsigned short* xseq  = (unsigned short*)(ws + O_A);
  float* xp             = (float*)(ws + O_A + 13107200);
  unsigned short* hout1 = (unsigned short*)(ws + O_A + 91750400);
  unsigned short* hout2 = (unsigned short*)(ws + O_A + 104857600);
  float* pooled         = (float*)(ws + O_A + 117964800);

  for (int l = 0; l < 3; ++l) {
    convT_k<<<dim3(8, 8), 256, 0, stream>>>(Wq + (size_t)l * 262144, WqT + (size_t)l * 262144, 512, 512);
    convT_k<<<dim3(8, 8), 256, 0, stream>>>(Wk + (size_t)l * 262144, WkT + (size_t)l * 262144, 512, 512);
    convT_k<<<dim3(8, 8), 256, 0, stream>>>(Wv + (size_t)l * 262144, WvT + (size_t)l * 262144, 512, 512);
    convT_k<<<dim3(8, 8), 256, 0, stream>>>(Wo + (size_t)l * 262144, WoT + (size_t)l * 262144, 512, 512);
    convT_k<<<dim3(8, 32), 256, 0, stream>>>(W1 + (size_t)l * 1048576, W1T + (size_t)l * 1048576, 512, 2048);
    convT_k<<<dim3(32, 8), 256, 0, stream>>>(W2 + (size_t)l * 1048576, W2T + (size_t)l * 1048576, 2048, 512);
  }
  convB_k<<<1024, 256, 0, stream>>>(Wih, WihB, 2 * 2 * 768 * 512);
  convB_k<<<512, 256, 0, stream>>>(Whh, WhhB, 2 * 2 * 768 * 256);

  embed_k<<<3200, 256, 0, stream>>>(x, emb, cur_f, cur_bf);

  for (int l = 0; l < 3; ++l) {
    gemm_k<0, 0, 0, 1><<<dim3(100, 4), 256, 0, stream>>>(cur_bf, WqT + (size_t)l * 262144, bq + l * 512, nullptr, nullptr, Qb, 12800, 512, 512);
    gemm_k<0, 0, 0, 1><<<dim3(100, 4), 256, 0, stream>>>(cur_bf, WkT + (size_t)l * 262144, bk + l * 512, nullptr, nullptr, Kb, 12800, 512, 512);
    gemm_k<0, 0, 0, 1><<<dim3(100, 4), 256, 0, stream>>>(cur_bf, WvT + (size_t)l * 262144, bv + l * 512, nullptr, nullptr, Vb, 12800, 512, 512);
    attn_k<<<1024, 256, 0, stream>>>(Qb, Kb, Vb, ctx);
    gemm_k<0, 1, 1, 0><<<dim3(100, 4), 256, 0, stream>>>(ctx, WoT + (size_t)l * 262144, bo + l * 512, cur_f, tmp_f, nullptr, 12800, 512, 512);
    ln_k<<<3200, 256, 0, stream>>>(tmp_f, g1 + l * 512, be1 + l * 512, cur_f, cur_bf);
    gemm_k<1, 0, 0, 1><<<dim3(100, 16), 256, 0, stream>>>(cur_bf, W1T + (size_t)l * 1048576, b1 + l * 2048, nullptr, nullptr, ff1, 12800, 2048, 512);
    gemm_k<0, 1, 1, 0><<<dim3(100, 4), 256, 0, stream>>>(ff1, W2T + (size_t)l * 1048576, b2 + l * 512, cur_f, tmp_f, nullptr, 12800, 512, 2048);
    ln_k<<<3200, 256, 0, stream>>>(tmp_f, g2 + l * 512, be2 + l * 512, cur_f, cur_bf);
  }

  // GRU stage (encoder scratch now dead; cbias written into WqT region)
  biasC_k<<<12, 256, 0, stream>>>(bih, bhh, cbias);
  seqT_k<<<12800, 128, 0, stream>>>(cur_bf, xseq);
  for (int l = 0; l < 2; ++l) {
    const unsigned short* Ain = (l == 0) ? xseq : hout1;
    for (int d = 0; d < 2; ++d)
      gemm_k<0, 0, 1, 0><<<dim3(100, 6), 256, 0, stream>>>(
          Ain, WihB + ((size_t)l * 2 + d) * 768 * 512, cbias + (l * 2 + d) * 768, nullptr,
          xp + (size_t)d * 9830400, nullptr, 12800, 768, 512);
    gru_k<<<16, 512, 0, stream>>>(WhhB + (size_t)l * 2 * 768 * 256, bhh + l * 2 * 768, xp,
                                  (l == 0) ? hout1 : hout2);
  }

  pool_k<<<128, 256, 0, stream>>>(cur_f, hout2, pooled);
  fc_k<<<128, 64, 0, stream>>>(pooled, fcW, fcb, (float*)d_out);
}